// Round 9
// baseline (810.230 us; speedup 1.0000x reference)
//
#include <hip/hip_runtime.h>

typedef unsigned int uint;
typedef unsigned short ushort;

typedef __attribute__((ext_vector_type(8))) short sh8;
typedef __attribute__((ext_vector_type(4))) float f32x4;

__device__ __forceinline__ ushort f2b(float f) {
    uint x = __float_as_uint(f);
    x += 0x7fffu + ((x >> 16) & 1u);
    return (ushort)(x >> 16);
}
__device__ __forceinline__ float b2f(ushort u) {
    return __uint_as_float(((uint)u) << 16);
}
__device__ __forceinline__ uint pack2(float a, float b) {
    return (uint)f2b(a) | ((uint)f2b(b) << 16);
}
// RTNE pack of two f32 -> two bf16 in one instruction.
__device__ __forceinline__ uint cvt_pk_bf16(float lo, float hi) {
    uint r;
    asm("v_cvt_pk_bf16_f32 %0, %1, %2" : "=v"(r) : "v"(lo), "v"(hi));
    return r;
}
__device__ __forceinline__ float frcp(float x) { return __builtin_amdgcn_rcpf(x); }
__device__ __forceinline__ float sigmf(float x) { return frcp(1.0f + __expf(-x)); }
__device__ __forceinline__ float tanhf2(float y) {
    return fmaf(2.0f, frcp(1.0f + __expf(-2.0f * y)), -1.0f);
}

// ---------------------------------------------------------------------------
// Index-width detector for x (robustness; x believed int32).
// ---------------------------------------------------------------------------
__global__ __launch_bounds__(256) void k_detx(const uint* __restrict__ xw,
                                              int* __restrict__ flag) {
    __shared__ int sh[256];
    int t = threadIdx.x;
    int c = 0;
    for (int i = t; i < 2048; i += 256) c += (xw[2 * i + 1] == 0u) ? 1 : 0;
    sh[t] = c;
    __syncthreads();
    if (t == 0) {
        int s = 0;
        for (int i = 0; i < 256; i++) s += sh[i];
        flag[0] = (s >= 1843) ? 1 : 0;  // >=90% zeros -> int64
    }
}

// ---------------------------------------------------------------------------
// Embedding gather, fp32 -> bf16, index-width aware.
// ---------------------------------------------------------------------------
__global__ __launch_bounds__(256) void k_gather(const void* __restrict__ x,
                                                const float* __restrict__ embed,
                                                const int* __restrict__ flag,
                                                ushort* __restrict__ out) {
    int chunk = blockIdx.x * 256 + threadIdx.x;
    int row = chunk >> 5;
    int c = chunk & 31;
    int v;
    if (flag[0]) {
        v = (int)((const uint*)x)[2 * row];
    } else {
        v = ((const int*)x)[row];
    }
    v = min(max(v, 0), 49999);
    const float4* e = (const float4*)&embed[(size_t)v * 256 + (size_t)c * 8];
    float4 a = e[0], b = e[1];
    uint4 pv;
    pv.x = pack2(a.x, a.y);
    pv.y = pack2(a.z, a.w);
    pv.z = pack2(b.x, b.y);
    pv.w = pack2(b.z, b.w);
    *(uint4*)&out[(size_t)row * 256 + (size_t)c * 8] = pv;
}

// ---------------------------------------------------------------------------
// GEMM (verified at baseline): C = A(bf16) * W^T(fp32 inline->bf16) + bias,
// optional GELU; bf16 Cb and/or fp32 Cf outputs. Plain __syncthreads.
// ---------------------------------------------------------------------------
__global__ __launch_bounds__(256) void k_gemm_bt(const ushort* __restrict__ A,
                                                 const float* __restrict__ Wf,
                                                 const float* __restrict__ bias,
                                                 ushort* __restrict__ Cb,
                                                 float* __restrict__ Cf,
                                                 int M, int N, int K, int gelu) {
    __shared__ __align__(16) ushort Al[128 * 32];
    __shared__ __align__(16) ushort Bl[128 * 32];
    int tid = threadIdx.x;
    int bm = blockIdx.x, bn = blockIdx.y;
    int wid = tid >> 6, lane = tid & 63;
    int ln = lane & 15, kq = lane >> 4;
    int wm = (wid & 1) * 64, wn = (wid >> 1) * 64;
    int rowA0 = bm * 128, rowB0 = bn * 128;

    f32x4 acc[4][4];
#pragma unroll
    for (int i = 0; i < 4; i++)
#pragma unroll
        for (int j = 0; j < 4; j++) acc[i][j] = (f32x4){0.f, 0.f, 0.f, 0.f};

    for (int kt = 0; kt < K; kt += 32) {
#pragma unroll
        for (int c = tid; c < 512; c += 256) {
            int r = c >> 2, c8 = (c & 3) * 8;
            *(uint4*)&Al[r * 32 + c8] =
                *(const uint4*)&A[(size_t)(rowA0 + r) * K + kt + c8];
            int nb = rowB0 + r;
            uint4 bv = {0u, 0u, 0u, 0u};
            if (nb < N) {
                const float4* wp = (const float4*)&Wf[(size_t)nb * K + kt + c8];
                float4 w0 = wp[0], w1 = wp[1];
                bv.x = pack2(w0.x, w0.y);
                bv.y = pack2(w0.z, w0.w);
                bv.z = pack2(w1.x, w1.y);
                bv.w = pack2(w1.z, w1.w);
            }
            *(uint4*)&Bl[r * 32 + c8] = bv;
        }
        __syncthreads();
        sh8 af[4], bfr[4];
#pragma unroll
        for (int i = 0; i < 4; i++)
            af[i] = *(const sh8*)&Al[(wm + i * 16 + ln) * 32 + kq * 8];
#pragma unroll
        for (int j = 0; j < 4; j++)
            bfr[j] = *(const sh8*)&Bl[(wn + j * 16 + ln) * 32 + kq * 8];
#pragma unroll
        for (int i = 0; i < 4; i++)
#pragma unroll
            for (int j = 0; j < 4; j++)
                acc[i][j] = __builtin_amdgcn_mfma_f32_16x16x32_bf16(
                    af[i], bfr[j], acc[i][j], 0, 0, 0);
        __syncthreads();
    }

#pragma unroll
    for (int i = 0; i < 4; i++)
#pragma unroll
        for (int j = 0; j < 4; j++) {
            int col = rowB0 + wn + j * 16 + ln;
            if (col >= N) continue;
            float bv = bias[col];
#pragma unroll
            for (int reg = 0; reg < 4; reg++) {
                int row = rowA0 + wm + i * 16 + kq * 4 + reg;
                float v = acc[i][j][reg] + bv;
                if (gelu) v = 0.5f * v * (1.0f + erff(v * 0.70710678118f));
                if (Cb) Cb[(size_t)row * N + col] = f2b(v);
                if (Cf) Cf[(size_t)row * N + col] = v;
            }
        }
}

// ---------------------------------------------------------------------------
// GRU recurrence v9b — 4 waves/block, 2 col-groups/wave (r8 bugfix).
// r8 FAILED (absmax 4e-2): bfrag was built gate-major (q=g*2+c) while the
// consumer assumes col-major (q=c*3+g) — five of six gate pre-activations
// permuted. Fix: build bfrag[c*3+g]. Everything else identical to r8:
// DS-drain halved (4 waves x 4 ds_read_b128; A-frags shared across a wave's
// 6 MFMA chains), each lane owns 2 outputs (b=kq, col=w*32+{0,16}+ln) with
// +32-byte immediates; replicated-A trick (A row=ln&3 => reg r = batch r,
// select reg kq); LDS [2][4][144] double-buffer; counted-vmcnt asm stream:
// 8 loads + 2 stores/step, waits 8, 10, steady 12, tail 12, 4 — never 0.
// ---------------------------------------------------------------------------
struct PF {
    uint xr0, xz0, xn0, rv0;
    uint xr1, xz1, xn1, rv1;
};

#define GLOAD(dst, off, base, IMM)                                            \
    asm volatile("global_load_ushort %0, %1, %2 offset:" IMM                  \
                 : "=v"(dst)                                                  \
                 : "v"(off), "s"(base))

#define GSTORE(off, data, base, IMM)                                          \
    asm volatile("global_store_short %0, %1, %2 offset:" IMM ::"v"(off),      \
                 "v"(data), "s"(base))

#define PREF(p)                                                               \
    {                                                                         \
        GLOAD(p.xr0, xo_ld, xp, "0");                                         \
        GLOAD(p.xz0, xo_ld, xp, "256");                                       \
        GLOAD(p.xn0, xo_ld, xp, "512");                                       \
        GLOAD(p.rv0, ho_ld, hb, "0");                                         \
        GLOAD(p.xr1, xo_ld, xp, "32");                                        \
        GLOAD(p.xz1, xo_ld, xp, "288");                                       \
        GLOAD(p.xn1, xo_ld, xp, "544");                                       \
        GLOAD(p.rv1, ho_ld, hb, "32");                                        \
        xo_ld += XS;                                                          \
        ho_ld += HS;                                                          \
    }

#define SEL(v) (b2 ? (b1 ? (v)[3] : (v)[2]) : (b1 ? (v)[1] : (v)[0]))

#define GSTEP(PAR, p, WN, DP)                                                 \
    {                                                                         \
        asm volatile("s_waitcnt vmcnt(" #WN ")");                             \
        __builtin_amdgcn_sched_barrier(0);                                    \
        float xr0 = __uint_as_float(p.xr0 << 16);                             \
        float xz0 = __uint_as_float(p.xz0 << 16);                             \
        float xn0 = __uint_as_float(p.xn0 << 16);                             \
        float rv0 = __uint_as_float(p.rv0 << 16);                             \
        float xr1 = __uint_as_float(p.xr1 << 16);                             \
        float xz1 = __uint_as_float(p.xz1 << 16);                             \
        float xn1 = __uint_as_float(p.xn1 << 16);                             \
        float rv1 = __uint_as_float(p.rv1 << 16);                             \
        if (DP) {                                                             \
            PREF(p)                                                           \
        }                                                                     \
        const ushort* hrd = lds + (PAR)*576 + (ln & 3) * 144 + kq * 8;        \
        sh8 a0 = *(const sh8*)(hrd);                                          \
        sh8 a1 = *(const sh8*)(hrd + 32);                                     \
        sh8 a2 = *(const sh8*)(hrd + 64);                                     \
        sh8 a3 = *(const sh8*)(hrd + 96);                                     \
        f32x4 ac[6];                                                          \
        _Pragma("unroll") for (int q_ = 0; q_ < 6; q_++)                      \
            ac[q_] = (f32x4){0.f, 0.f, 0.f, 0.f};                             \
        ac[0] = __builtin_amdgcn_mfma_f32_16x16x32_bf16(a0, bfrag[0][0], ac[0], 0, 0, 0); \
        ac[1] = __builtin_amdgcn_mfma_f32_16x16x32_bf16(a0, bfrag[1][0], ac[1], 0, 0, 0); \
        ac[2] = __builtin_amdgcn_mfma_f32_16x16x32_bf16(a0, bfrag[2][0], ac[2], 0, 0, 0); \
        ac[3] = __builtin_amdgcn_mfma_f32_16x16x32_bf16(a0, bfrag[3][0], ac[3], 0, 0, 0); \
        ac[4] = __builtin_amdgcn_mfma_f32_16x16x32_bf16(a0, bfrag[4][0], ac[4], 0, 0, 0); \
        ac[5] = __builtin_amdgcn_mfma_f32_16x16x32_bf16(a0, bfrag[5][0], ac[5], 0, 0, 0); \
        ac[0] = __builtin_amdgcn_mfma_f32_16x16x32_bf16(a1, bfrag[0][1], ac[0], 0, 0, 0); \
        ac[1] = __builtin_amdgcn_mfma_f32_16x16x32_bf16(a1, bfrag[1][1], ac[1], 0, 0, 0); \
        ac[2] = __builtin_amdgcn_mfma_f32_16x16x32_bf16(a1, bfrag[2][1], ac[2], 0, 0, 0); \
        ac[3] = __builtin_amdgcn_mfma_f32_16x16x32_bf16(a1, bfrag[3][1], ac[3], 0, 0, 0); \
        ac[4] = __builtin_amdgcn_mfma_f32_16x16x32_bf16(a1, bfrag[4][1], ac[4], 0, 0, 0); \
        ac[5] = __builtin_amdgcn_mfma_f32_16x16x32_bf16(a1, bfrag[5][1], ac[5], 0, 0, 0); \
        ac[0] = __builtin_amdgcn_mfma_f32_16x16x32_bf16(a2, bfrag[0][2], ac[0], 0, 0, 0); \
        ac[1] = __builtin_amdgcn_mfma_f32_16x16x32_bf16(a2, bfrag[1][2], ac[1], 0, 0, 0); \
        ac[2] = __builtin_amdgcn_mfma_f32_16x16x32_bf16(a2, bfrag[2][2], ac[2], 0, 0, 0); \
        ac[3] = __builtin_amdgcn_mfma_f32_16x16x32_bf16(a2, bfrag[3][2], ac[3], 0, 0, 0); \
        ac[4] = __builtin_amdgcn_mfma_f32_16x16x32_bf16(a2, bfrag[4][2], ac[4], 0, 0, 0); \
        ac[5] = __builtin_amdgcn_mfma_f32_16x16x32_bf16(a2, bfrag[5][2], ac[5], 0, 0, 0); \
        ac[0] = __builtin_amdgcn_mfma_f32_16x16x32_bf16(a3, bfrag[0][3], ac[0], 0, 0, 0); \
        ac[1] = __builtin_amdgcn_mfma_f32_16x16x32_bf16(a3, bfrag[1][3], ac[1], 0, 0, 0); \
        ac[2] = __builtin_amdgcn_mfma_f32_16x16x32_bf16(a3, bfrag[2][3], ac[2], 0, 0, 0); \
        ac[3] = __builtin_amdgcn_mfma_f32_16x16x32_bf16(a3, bfrag[3][3], ac[3], 0, 0, 0); \
        ac[4] = __builtin_amdgcn_mfma_f32_16x16x32_bf16(a3, bfrag[4][3], ac[4], 0, 0, 0); \
        ac[5] = __builtin_amdgcn_mfma_f32_16x16x32_bf16(a3, bfrag[5][3], ac[5], 0, 0, 0); \
        float ar0 = SEL(ac[0]), az0 = SEL(ac[1]), an0 = SEL(ac[2]);           \
        float ar1 = SEL(ac[3]), az1 = SEL(ac[4]), an1 = SEL(ac[5]);           \
        float rg0 = sigmf(xr0 + ar0 + bh_r0);                                 \
        float zg0 = sigmf(xz0 + az0 + bh_z0);                                 \
        float ng0 = tanhf2(fmaf(rg0, an0 + bh_n0, xn0));                      \
        float h0 = fmaf(zg0, hst0 - ng0, ng0);                                \
        hst0 = h0;                                                            \
        float rg1 = sigmf(xr1 + ar1 + bh_r1);                                 \
        float zg1 = sigmf(xz1 + az1 + bh_z1);                                 \
        float ng1 = tanhf2(fmaf(rg1, an1 + bh_n1, xn1));                      \
        float h1 = fmaf(zg1, hst1 - ng1, ng1);                                \
        hst1 = h1;                                                            \
        uint pk0 = cvt_pk_bf16(h0, h0 + rv0);                                 \
        uint pk1 = cvt_pk_bf16(h1, h1 + rv1);                                 \
        ushort* hw = lds + (1 - (PAR)) * 576 + kq * 144 + wb + ln;            \
        hw[0] = (ushort)pk0;                                                  \
        hw[16] = (ushort)pk1;                                                 \
        uint sv0 = pk0 >> 16, sv1 = pk1 >> 16;                                \
        GSTORE(ho_st, sv0, hb, "0");                                          \
        GSTORE(ho_st, sv1, hb, "32");                                         \
        ho_st += HS;                                                          \
        asm volatile("s_waitcnt lgkmcnt(0)");                                 \
        __builtin_amdgcn_sched_barrier(0);                                    \
        __builtin_amdgcn_s_barrier();                                         \
        __builtin_amdgcn_sched_barrier(0);                                    \
    }

template <int DS>  // +1 forward, -1 backward
__device__ __forceinline__ void gru_impl(const ushort* __restrict__ xp,
                                         const float* __restrict__ Whh_l,
                                         const float* __restrict__ bhh_l,
                                         ushort* __restrict__ hb,
                                         int dir, int b_base, int t,
                                         ushort* lds) {
    constexpr int XS = DS * 1536;  // xp row stride per time step, bytes
    constexpr int HS = DS * 512;   // hb row stride per time step, bytes
    const int w = t >> 6, l = t & 63;
    const int ln = l & 15, kq = l >> 4;
    const int wb = w * 32;           // this wave's 32-col base
    const bool b1 = (kq & 1) != 0, b2 = (kq & 2) != 0;

    const float* Wd = Whh_l + (size_t)dir * 384 * 128;
    const float* bhh_d = bhh_l + dir * 384;

    // Whh B-fragments: 6 chains x 4 k-tiles, COL-MAJOR chain index
    // q = c*3 + g (ac[0..2] = r,z,n of col-group 0; ac[3..5] = col-group 1).
    // r8's bug was building this gate-major (q = g*2+c).
    sh8 bfrag[6][4];
#pragma unroll
    for (int g = 0; g < 3; g++)
#pragma unroll
        for (int c = 0; c < 2; c++)
#pragma unroll
            for (int kt = 0; kt < 4; kt++) {
                const float4* wp = (const float4*)(
                    Wd + (size_t)(g * 128 + wb + c * 16 + ln) * 128 + kt * 32 +
                    kq * 8);
                float4 w0 = wp[0], w1 = wp[1];
                uint4 pv;
                pv.x = pack2(w0.x, w0.y);
                pv.y = pack2(w0.z, w0.w);
                pv.z = pack2(w1.x, w1.y);
                pv.w = pack2(w1.z, w1.w);
                bfrag[c * 3 + g][kt] = *(sh8*)&pv;
            }

    const float bh_r0 = bhh_d[wb + ln];
    const float bh_z0 = bhh_d[128 + wb + ln];
    const float bh_n0 = bhh_d[256 + wb + ln];
    const float bh_r1 = bhh_d[wb + 16 + ln];
    const float bh_z1 = bhh_d[128 + wb + 16 + ln];
    const float bh_n1 = bhh_d[256 + wb + 16 + ln];
    asm volatile("" ::"v"(bh_r0), "v"(bh_z0), "v"(bh_n0), "v"(bh_r1),
                 "v"(bh_z1), "v"(bh_n1));

    // Running byte voffsets; this lane's outputs: (b_base+kq, wb+ln) and
    // (b_base+kq, wb+16+ln) — the 2nd reached via +32-byte immediates.
    const int t0 = (DS > 0) ? 0 : 511;
    int row0 = (b_base + kq) * 512 + t0;
    int xo_ld = row0 * 1536 + (dir * 384 + wb + ln) * 2;
    int ho_ld = row0 * 512 + (dir * 128 + wb + ln) * 2;
    int ho_st = ho_ld;

    float hst0 = 0.f, hst1 = 0.f;

    // zero both h buffers (2 x 4 rows x 144)
    for (int i = t; i < 2 * 576; i += 256) lds[i] = 0;
    __syncthreads();  // full drain; vmcnt==0 from here

    PF pA, pB;
    PREF(pA)  // t0   (8 loads)
    PREF(pB)  // t0+1 (8 loads)

    GSTEP(0, pA, 8, 1)   // s = 0
    GSTEP(1, pB, 10, 1)  // s = 1
    for (int s = 2; s < 510; s += 2) {
        GSTEP(0, pA, 12, 1)
        GSTEP(1, pB, 12, 1)
    }
    GSTEP(0, pA, 12, 0)  // s = 510 (no prefetch)
    GSTEP(1, pB, 4, 0)   // s = 511
}

__global__ __launch_bounds__(256, 1) void k_gru(const ushort* __restrict__ xp,
                                                const float* __restrict__ Whh_l,
                                                const float* __restrict__ bhh_l,
                                                ushort* __restrict__ hb) {
    __shared__ __align__(16) ushort lds[2 * 576];
    const int dir = blockIdx.x & 1;
    const int b_base = (blockIdx.x >> 1) << 2;  // 4 batches per block
    if (dir == 0)
        gru_impl<1>(xp, Whh_l, bhh_l, hb, dir, b_base, threadIdx.x, lds);
    else
        gru_impl<-1>(xp, Whh_l, bhh_l, hb, dir, b_base, threadIdx.x, lds);
}

// ---------------------------------------------------------------------------
// Host launcher. fp32 inputs AND fp32 output; bf16 internally for MFMA.
// Scratch confined to 64 MiB:
//   [0, 48M)  xp (bf16 32768x768) — also hosts embA, then g (16 MiB each)
//   [48,64M)  hb (bf16 32768x256) — W1 out, GRU layers update in place
// ---------------------------------------------------------------------------
extern "C" void kernel_launch(void* const* d_in, const int* in_sizes, int n_in,
                              void* d_out, int out_size, void* d_ws, size_t ws_size,
                              hipStream_t stream) {
    const void* x = d_in[0];
    const float* embed = (const float*)d_in[1];
    const float* W1 = (const float*)d_in[2];
    const float* b1 = (const float*)d_in[3];
    const float* Wih = (const float*)d_in[4];  // [2][2][384][256]
    const float* Whh = (const float*)d_in[5];  // [2][2][384][128]
    const float* bih = (const float*)d_in[6];  // [2][2][384]
    const float* bhh = (const float*)d_in[7];  // [2][2][384]
    const float* W2 = (const float*)d_in[8];
    const float* b2 = (const float*)d_in[9];
    const float* W3 = (const float*)d_in[10];
    const float* b3 = (const float*)d_in[11];

    char* ws = (char*)d_ws;
    ushort* xp = (ushort*)ws;                         // [0, 48M)
    ushort* hb = (ushort*)(ws + 32768ull * 768 * 2);  // [48M, 64M)
    ushort* embA = xp;  // 16 MiB slot, dead after W1 GEMM
    ushort* g = xp;     // reused after last GRU
    int* xflag = (int*)hb;  // transient; dead after k_gather

    // detect x index width, then gather + W1: hb = bf16(embA @ W1^T + b1)
    k_detx<<<1, 256, 0, stream>>>((const uint*)x, xflag);
    k_gather<<<4096, 256, 0, stream>>>(x, embed, xflag, embA);
    k_gemm_bt<<<dim3(256, 2), 256, 0, stream>>>(embA, W1, b1, hb, (float*)0,
                                                32768, 256, 256, 0);

    // layer 0: xp = hb @ Wih[0]^T + bih[0]; GRU updates hb in place
    k_gemm_bt<<<dim3(256, 6), 256, 0, stream>>>(hb, Wih, bih, xp, (float*)0,
                                                32768, 768, 256, 0);
    k_gru<<<32, 256, 0, stream>>>(xp, Whh, bhh, hb);

    // layer 1
    k_gemm_bt<<<dim3(256, 6), 256, 0, stream>>>(hb, Wih + 196608, bih + 768,
                                                xp, (float*)0, 32768, 768, 256, 0);
    k_gru<<<32, 256, 0, stream>>>(xp, Whh + 98304, bhh + 768, hb);

    // head: g = bf16(GELU(hb @ W2^T + b2)); d_out = fp32(g @ W3^T + b3)
    k_gemm_bt<<<dim3(256, 2), 256, 0, stream>>>(hb, W2, b2, g, (float*)0,
                                                32768, 256, 256, 1);
    k_gemm_bt<<<dim3(256, 1), 256, 0, stream>>>(g, W3, b3, (ushort*)0,
                                                (float*)d_out, 32768, 50, 256, 0);
}

// Round 11
// 668.554 us; speedup vs baseline: 1.2119x; 1.2119x over previous
//
#include <hip/hip_runtime.h>

typedef unsigned int uint;
typedef unsigned short ushort;

typedef __attribute__((ext_vector_type(8))) short sh8;
typedef __attribute__((ext_vector_type(4))) float f32x4;

__device__ __forceinline__ ushort f2b(float f) {
    uint x = __float_as_uint(f);
    x += 0x7fffu + ((x >> 16) & 1u);
    return (ushort)(x >> 16);
}
__device__ __forceinline__ float b2f(ushort u) {
    return __uint_as_float(((uint)u) << 16);
}
__device__ __forceinline__ uint pack2(float a, float b) {
    return (uint)f2b(a) | ((uint)f2b(b) << 16);
}
// RTNE pack of two f32 -> two bf16 in one instruction.
__device__ __forceinline__ uint cvt_pk_bf16(float lo, float hi) {
    uint r;
    asm("v_cvt_pk_bf16_f32 %0, %1, %2" : "=v"(r) : "v"(lo), "v"(hi));
    return r;
}
__device__ __forceinline__ float frcp(float x) { return __builtin_amdgcn_rcpf(x); }
__device__ __forceinline__ float sigmf(float x) { return frcp(1.0f + __expf(-x)); }
__device__ __forceinline__ float tanhf2(float y) {
    return fmaf(2.0f, frcp(1.0f + __expf(-2.0f * y)), -1.0f);
}

// ---------------------------------------------------------------------------
// Index-width detector for x (robustness; x believed int32).
// ---------------------------------------------------------------------------
__global__ __launch_bounds__(256) void k_detx(const uint* __restrict__ xw,
                                              int* __restrict__ flag) {
    __shared__ int sh[256];
    int t = threadIdx.x;
    int c = 0;
    for (int i = t; i < 2048; i += 256) c += (xw[2 * i + 1] == 0u) ? 1 : 0;
    sh[t] = c;
    __syncthreads();
    if (t == 0) {
        int s = 0;
        for (int i = 0; i < 256; i++) s += sh[i];
        flag[0] = (s >= 1843) ? 1 : 0;  // >=90% zeros -> int64
    }
}

// ---------------------------------------------------------------------------
// Embedding gather, fp32 -> bf16, index-width aware.
// ---------------------------------------------------------------------------
__global__ __launch_bounds__(256) void k_gather(const void* __restrict__ x,
                                                const float* __restrict__ embed,
                                                const int* __restrict__ flag,
                                                ushort* __restrict__ out) {
    int chunk = blockIdx.x * 256 + threadIdx.x;
    int row = chunk >> 5;
    int c = chunk & 31;
    int v;
    if (flag[0]) {
        v = (int)((const uint*)x)[2 * row];
    } else {
        v = ((const int*)x)[row];
    }
    v = min(max(v, 0), 49999);
    const float4* e = (const float4*)&embed[(size_t)v * 256 + (size_t)c * 8];
    float4 a = e[0], b = e[1];
    uint4 pv;
    pv.x = pack2(a.x, a.y);
    pv.y = pack2(a.z, a.w);
    pv.z = pack2(b.x, b.y);
    pv.w = pack2(b.z, b.w);
    *(uint4*)&out[(size_t)row * 256 + (size_t)c * 8] = pv;
}

// ---------------------------------------------------------------------------
// GEMM: C = A(bf16) * W^T(fp32 inline->bf16) + bias, optional GELU; bf16 Cb
// and/or fp32 Cf outputs. NEW vs r7: A-tile staged via async
// global_load_lds width=16 (m97 pattern). Our layout already satisfies the
// HW constraint: thread tid's LDS dest = byte 16*tid (wave-uniform base +
// lane*16, contiguous); global src is per-lane. B-tile keeps the reg path
// (needs fp32->bf16 VALU convert). __syncthreads drains vmcnt+lgkmcnt, so
// the existing two barriers cover both visibility and anti-overwrite.
// ---------------------------------------------------------------------------
#define GLDS16(gsrc, ldst)                                                    \
    __builtin_amdgcn_global_load_lds(                                         \
        (const __attribute__((address_space(1))) uint*)(gsrc),                \
        (__attribute__((address_space(3))) uint*)(ldst), 16, 0, 0)

__global__ __launch_bounds__(256) void k_gemm_bt(const ushort* __restrict__ A,
                                                 const float* __restrict__ Wf,
                                                 const float* __restrict__ bias,
                                                 ushort* __restrict__ Cb,
                                                 float* __restrict__ Cf,
                                                 int M, int N, int K, int gelu) {
    __shared__ __align__(16) ushort Al[128 * 32];
    __shared__ __align__(16) ushort Bl[128 * 32];
    int tid = threadIdx.x;
    int bm = blockIdx.x, bn = blockIdx.y;
    int wid = tid >> 6, lane = tid & 63;
    int ln = lane & 15, kq = lane >> 4;
    int wm = (wid & 1) * 64, wn = (wid >> 1) * 64;
    int rowA0 = bm * 128, rowB0 = bn * 128;

    f32x4 acc[4][4];
#pragma unroll
    for (int i = 0; i < 4; i++)
#pragma unroll
        for (int j = 0; j < 4; j++) acc[i][j] = (f32x4){0.f, 0.f, 0.f, 0.f};

    int ra = tid >> 2, ca8 = (tid & 3) * 8;  // A-staging coords (16B/lane)

    for (int kt = 0; kt < K; kt += 32) {
        // A tile: async global->LDS, 2 x 16B per thread.
        GLDS16(&A[(size_t)(rowA0 + ra) * K + kt + ca8], &Al[tid * 8]);
        GLDS16(&A[(size_t)(rowA0 + 64 + ra) * K + kt + ca8],
               &Al[2048 + tid * 8]);
        // B tile: reg path with inline fp32->bf16.
#pragma unroll
        for (int c = tid; c < 512; c += 256) {
            int r = c >> 2, c8 = (c & 3) * 8;
            int nb = rowB0 + r;
            uint4 bv = {0u, 0u, 0u, 0u};
            if (nb < N) {
                const float4* wp = (const float4*)&Wf[(size_t)nb * K + kt + c8];
                float4 w0 = wp[0], w1 = wp[1];
                bv.x = pack2(w0.x, w0.y);
                bv.y = pack2(w0.z, w0.w);
                bv.z = pack2(w1.x, w1.y);
                bv.w = pack2(w1.z, w1.w);
            }
            *(uint4*)&Bl[r * 32 + c8] = bv;
        }
        __syncthreads();
        sh8 af[4], bfr[4];
#pragma unroll
        for (int i = 0; i < 4; i++)
            af[i] = *(const sh8*)&Al[(wm + i * 16 + ln) * 32 + kq * 8];
#pragma unroll
        for (int j = 0; j < 4; j++)
            bfr[j] = *(const sh8*)&Bl[(wn + j * 16 + ln) * 32 + kq * 8];
#pragma unroll
        for (int i = 0; i < 4; i++)
#pragma unroll
            for (int j = 0; j < 4; j++)
                acc[i][j] = __builtin_amdgcn_mfma_f32_16x16x32_bf16(
                    af[i], bfr[j], acc[i][j], 0, 0, 0);
        __syncthreads();
    }

#pragma unroll
    for (int i = 0; i < 4; i++)
#pragma unroll
        for (int j = 0; j < 4; j++) {
            int col = rowB0 + wn + j * 16 + ln;
            if (col >= N) continue;
            float bv = bias[col];
#pragma unroll
            for (int reg = 0; reg < 4; reg++) {
                int row = rowA0 + wm + i * 16 + kq * 4 + reg;
                float v = acc[i][j][reg] + bv;
                if (gelu) v = 0.5f * v * (1.0f + erff(v * 0.70710678118f));
                if (Cb) Cb[(size_t)row * N + col] = f2b(v);
                if (Cf) Cf[(size_t)row * N + col] = v;
            }
        }
}

// ---------------------------------------------------------------------------
// GRU recurrence v8 — EXACT r7-verified kernel (216 us/dispatch, absmax
// 0.00195). r9 (4 waves) and r10 (d16_hi loads) both lost; this structure
// is the local optimum: 32 blocks (4 batches x 1 dir), 512 threads, 1
// output/lane, 12 MFMA/wave, replicated-A (A row = ln&3 => C reg r = batch
// r, select reg kq; zero cross-lane redistribution), LDS [2][4][144]
// double-buffer (broadcast reads, conflict-free), counted-vmcnt asm stream:
// 4 loads + 1 store per step, distance-2 prefetch, waits 4,5,6,...,6,2.
// ---------------------------------------------------------------------------
struct PF {
    uint xr, xz, xn, rv;
};

#define GLOAD(dst, off, base, IMM)                                            \
    asm volatile("global_load_ushort %0, %1, %2 offset:" IMM                  \
                 : "=v"(dst)                                                  \
                 : "v"(off), "s"(base))

#define GSTORE(off, data, base)                                               \
    asm volatile("global_store_short %0, %1, %2" ::"v"(off), "v"(data),       \
                 "s"(base))

#define PREF(p)                                                               \
    {                                                                         \
        GLOAD(p.xr, xo_ld, xp, "0");                                          \
        GLOAD(p.xz, xo_ld, xp, "256");                                        \
        GLOAD(p.xn, xo_ld, xp, "512");                                        \
        GLOAD(p.rv, ho_ld, hb, "0");                                          \
        xo_ld += XS;                                                          \
        ho_ld += HS;                                                          \
    }

#define GSTEP(PAR, p, WN, DP)                                                 \
    {                                                                         \
        asm volatile("s_waitcnt vmcnt(" #WN ")");                             \
        __builtin_amdgcn_sched_barrier(0);                                    \
        float xr = __uint_as_float(p.xr << 16);                               \
        float xz = __uint_as_float(p.xz << 16);                               \
        float xn = __uint_as_float(p.xn << 16);                               \
        float rv = __uint_as_float(p.rv << 16);                               \
        if (DP) {                                                             \
            PREF(p)                                                           \
        }                                                                     \
        const ushort* hrd = lds + (PAR)*576 + (ln & 3) * 144 + kq * 8;        \
        sh8 a0 = *(const sh8*)(hrd);                                          \
        sh8 a1 = *(const sh8*)(hrd + 32);                                     \
        sh8 a2 = *(const sh8*)(hrd + 64);                                     \
        sh8 a3 = *(const sh8*)(hrd + 96);                                     \
        f32x4 accr = (f32x4){0.f, 0.f, 0.f, 0.f};                             \
        f32x4 accz = accr, accn = accr;                                       \
        accr = __builtin_amdgcn_mfma_f32_16x16x32_bf16(a0, bfrag[0][0], accr, 0, 0, 0); \
        accz = __builtin_amdgcn_mfma_f32_16x16x32_bf16(a0, bfrag[1][0], accz, 0, 0, 0); \
        accn = __builtin_amdgcn_mfma_f32_16x16x32_bf16(a0, bfrag[2][0], accn, 0, 0, 0); \
        accr = __builtin_amdgcn_mfma_f32_16x16x32_bf16(a1, bfrag[0][1], accr, 0, 0, 0); \
        accz = __builtin_amdgcn_mfma_f32_16x16x32_bf16(a1, bfrag[1][1], accz, 0, 0, 0); \
        accn = __builtin_amdgcn_mfma_f32_16x16x32_bf16(a1, bfrag[2][1], accn, 0, 0, 0); \
        accr = __builtin_amdgcn_mfma_f32_16x16x32_bf16(a2, bfrag[0][2], accr, 0, 0, 0); \
        accz = __builtin_amdgcn_mfma_f32_16x16x32_bf16(a2, bfrag[1][2], accz, 0, 0, 0); \
        accn = __builtin_amdgcn_mfma_f32_16x16x32_bf16(a2, bfrag[2][2], accn, 0, 0, 0); \
        accr = __builtin_amdgcn_mfma_f32_16x16x32_bf16(a3, bfrag[0][3], accr, 0, 0, 0); \
        accz = __builtin_amdgcn_mfma_f32_16x16x32_bf16(a3, bfrag[1][3], accz, 0, 0, 0); \
        accn = __builtin_amdgcn_mfma_f32_16x16x32_bf16(a3, bfrag[2][3], accn, 0, 0, 0); \
        float ar = b2 ? (b1 ? accr[3] : accr[2]) : (b1 ? accr[1] : accr[0]);  \
        float az = b2 ? (b1 ? accz[3] : accz[2]) : (b1 ? accz[1] : accz[0]);  \
        float an = b2 ? (b1 ? accn[3] : accn[2]) : (b1 ? accn[1] : accn[0]);  \
        float rg = sigmf(xr + ar + bh_r);                                     \
        float zg = sigmf(xz + az + bh_z);                                     \
        float ng = tanhf2(fmaf(rg, an + bh_n, xn));                           \
        float h = fmaf(zg, hstate - ng, ng);                                  \
        hstate = h;                                                           \
        float sv = h + rv;                                                    \
        uint pk = cvt_pk_bf16(h, sv);                                         \
        lds[(1 - (PAR)) * 576 + ob * 144 + jcol] = (ushort)pk;                \
        uint svb = pk >> 16;                                                  \
        GSTORE(ho_st, svb, hb);                                               \
        ho_st += HS;                                                          \
        asm volatile("s_waitcnt lgkmcnt(0)");                                 \
        __builtin_amdgcn_sched_barrier(0);                                    \
        __builtin_amdgcn_s_barrier();                                         \
        __builtin_amdgcn_sched_barrier(0);                                    \
    }

template <int DS>  // +1 forward, -1 backward
__device__ __forceinline__ void gru_impl(const ushort* __restrict__ xp,
                                         const float* __restrict__ Whh_l,
                                         const float* __restrict__ bhh_l,
                                         ushort* __restrict__ hb,
                                         int dir, int b_base, int t,
                                         ushort* lds) {
    constexpr int XS = DS * 1536;  // xp row stride per time step, bytes
    constexpr int HS = DS * 512;   // hb row stride per time step, bytes
    const int w = t >> 6, l = t & 63;
    const int ln = l & 15, kq = l >> 4;
    const int jcol = (w << 4) + ln;  // output col (and B-frag row)
    const int ob = kq;               // output batch index 0..3
    const bool b1 = (ob & 1) != 0, b2 = (ob & 2) != 0;

    const float* Wd = Whh_l + (size_t)dir * 384 * 128;
    const float* bhh_d = bhh_l + dir * 384;

    // Whh B-fragments, bf16, resident in VGPRs.
    sh8 bfrag[3][4];
#pragma unroll
    for (int g = 0; g < 3; g++)
#pragma unroll
        for (int kt = 0; kt < 4; kt++) {
            const float4* wp =
                (const float4*)(Wd + (size_t)(g * 128 + jcol) * 128 + kt * 32 + kq * 8);
            float4 w0 = wp[0], w1 = wp[1];
            uint4 pv;
            pv.x = pack2(w0.x, w0.y);
            pv.y = pack2(w0.z, w0.w);
            pv.z = pack2(w1.x, w1.y);
            pv.w = pack2(w1.z, w1.w);
            bfrag[g][kt] = *(sh8*)&pv;
        }

    const float bh_r = bhh_d[jcol];
    const float bh_z = bhh_d[128 + jcol];
    const float bh_n = bhh_d[256 + jcol];
    asm volatile("" ::"v"(bh_r), "v"(bh_z), "v"(bh_n));

    // Running byte voffsets for THIS lane's single output (b_base+ob, jcol).
    const int t0 = (DS > 0) ? 0 : 511;
    int row0 = (b_base + ob) * 512 + t0;
    int xo_ld = row0 * 1536 + (dir * 384 + jcol) * 2;
    int ho_ld = row0 * 512 + (dir * 128 + jcol) * 2;
    int ho_st = ho_ld;

    float hstate = 0.f;

    // zero both h buffers (2 x 4 rows x 144)
    for (int i = t; i < 2 * 576; i += 512) lds[i] = 0;
    __syncthreads();  // full drain; vmcnt==0 from here

    PF pA, pB;
    PREF(pA)  // t0   (4 loads)
    PREF(pB)  // t0+1 (4 loads)

    GSTEP(0, pA, 4, 1)  // s = 0
    GSTEP(1, pB, 5, 1)  // s = 1
    for (int s = 2; s < 510; s += 2) {
        GSTEP(0, pA, 6, 1)
        GSTEP(1, pB, 6, 1)
    }
    GSTEP(0, pA, 6, 0)  // s = 510 (no prefetch)
    GSTEP(1, pB, 2, 0)  // s = 511
}

__global__ __launch_bounds__(512, 1) void k_gru(const ushort* __restrict__ xp,
                                                const float* __restrict__ Whh_l,
                                                const float* __restrict__ bhh_l,
                                                ushort* __restrict__ hb) {
    __shared__ __align__(16) ushort lds[2 * 576];
    const int dir = blockIdx.x & 1;
    const int b_base = (blockIdx.x >> 1) << 2;  // 4 batches per block
    if (dir == 0)
        gru_impl<1>(xp, Whh_l, bhh_l, hb, dir, b_base, threadIdx.x, lds);
    else
        gru_impl<-1>(xp, Whh_l, bhh_l, hb, dir, b_base, threadIdx.x, lds);
}

// ---------------------------------------------------------------------------
// Host launcher. fp32 inputs AND fp32 output; bf16 internally for MFMA.
// Scratch confined to 64 MiB:
//   [0, 48M)  xp (bf16 32768x768) — also hosts embA, then g (16 MiB each)
//   [48,64M)  hb (bf16 32768x256) — W1 out, GRU layers update in place
// ---------------------------------------------------------------------------
extern "C" void kernel_launch(void* const* d_in, const int* in_sizes, int n_in,
                              void* d_out, int out_size, void* d_ws, size_t ws_size,
                              hipStream_t stream) {
    const void* x = d_in[0];
    const float* embed = (const float*)d_in[1];
    const float* W1 = (const float*)d_in[2];
    const float* b1 = (const float*)d_in[3];
    const float* Wih = (const float*)d_in[4];  // [2][2][384][256]
    const float* Whh = (const float*)d_in[5];  // [2][2][384][128]
    const float* bih = (const float*)d_in[6];  // [2][2][384]
    const float* bhh = (const float*)d_in[7];  // [2][2][384]
    const float* W2 = (const float*)d_in[8];
    const float* b2 = (const float*)d_in[9];
    const float* W3 = (const float*)d_in[10];
    const float* b3 = (const float*)d_in[11];

    char* ws = (char*)d_ws;
    ushort* xp = (ushort*)ws;                         // [0, 48M)
    ushort* hb = (ushort*)(ws + 32768ull * 768 * 2);  // [48M, 64M)
    ushort* embA = xp;  // 16 MiB slot, dead after W1 GEMM
    ushort* g = xp;     // reused after last GRU
    int* xflag = (int*)hb;  // transient; dead after k_gather

    // detect x index width, then gather + W1: hb = bf16(embA @ W1^T + b1)
    k_detx<<<1, 256, 0, stream>>>((const uint*)x, xflag);
    k_gather<<<4096, 256, 0, stream>>>(x, embed, xflag, embA);
    k_gemm_bt<<<dim3(256, 2), 256, 0, stream>>>(embA, W1, b1, hb, (float*)0,
                                                32768, 256, 256, 0);

    // layer 0: xp = hb @ Wih[0]^T + bih[0]; GRU updates hb in place
    k_gemm_bt<<<dim3(256, 6), 256, 0, stream>>>(hb, Wih, bih, xp, (float*)0,
                                                32768, 768, 256, 0);
    k_gru<<<32, 512, 0, stream>>>(xp, Whh, bhh, hb);

    // layer 1
    k_gemm_bt<<<dim3(256, 6), 256, 0, stream>>>(hb, Wih + 196608, bih + 768,
                                                xp, (float*)0, 32768, 768, 256, 0);
    k_gru<<<32, 512, 0, stream>>>(xp, Whh + 98304, bhh + 768, hb);

    // head: g = bf16(GELU(hb @ W2^T + b2)); d_out = fp32(g @ W3^T + b3)
    k_gemm_bt<<<dim3(256, 2), 256, 0, stream>>>(hb, W2, b2, g, (float*)0,
                                                32768, 256, 256, 1);
    k_gemm_bt<<<dim3(256, 1), 256, 0, stream>>>(g, W3, b3, (ushort*)0,
                                                (float*)d_out, 32768, 50, 256, 0);
}

// Round 12
// 643.612 us; speedup vs baseline: 1.2589x; 1.0388x over previous
//
#include <hip/hip_runtime.h>

typedef unsigned int uint;
typedef unsigned short ushort;

typedef __attribute__((ext_vector_type(8))) short sh8;
typedef __attribute__((ext_vector_type(4))) float f32x4;

__device__ __forceinline__ ushort f2b(float f) {
    uint x = __float_as_uint(f);
    x += 0x7fffu + ((x >> 16) & 1u);
    return (ushort)(x >> 16);
}
__device__ __forceinline__ float b2f(ushort u) {
    return __uint_as_float(((uint)u) << 16);
}
__device__ __forceinline__ uint pack2(float a, float b) {
    return (uint)f2b(a) | ((uint)f2b(b) << 16);
}
// RTNE pack of two f32 -> two bf16 in one instruction.
__device__ __forceinline__ uint cvt_pk_bf16(float lo, float hi) {
    uint r;
    asm("v_cvt_pk_bf16_f32 %0, %1, %2" : "=v"(r) : "v"(lo), "v"(hi));
    return r;
}
__device__ __forceinline__ float frcp(float x) { return __builtin_amdgcn_rcpf(x); }
__device__ __forceinline__ float sigmf(float x) { return frcp(1.0f + __expf(-x)); }
__device__ __forceinline__ float tanhf2(float y) {
    return fmaf(2.0f, frcp(1.0f + __expf(-2.0f * y)), -1.0f);
}

// ---------------------------------------------------------------------------
// Index-width detector for x (robustness; x believed int32).
// ---------------------------------------------------------------------------
__global__ __launch_bounds__(256) void k_detx(const uint* __restrict__ xw,
                                              int* __restrict__ flag) {
    __shared__ int sh[256];
    int t = threadIdx.x;
    int c = 0;
    for (int i = t; i < 2048; i += 256) c += (xw[2 * i + 1] == 0u) ? 1 : 0;
    sh[t] = c;
    __syncthreads();
    if (t == 0) {
        int s = 0;
        for (int i = 0; i < 256; i++) s += sh[i];
        flag[0] = (s >= 1843) ? 1 : 0;  // >=90% zeros -> int64
    }
}

// ---------------------------------------------------------------------------
// Embedding gather, fp32 -> bf16, index-width aware.
// ---------------------------------------------------------------------------
__global__ __launch_bounds__(256) void k_gather(const void* __restrict__ x,
                                                const float* __restrict__ embed,
                                                const int* __restrict__ flag,
                                                ushort* __restrict__ out) {
    int chunk = blockIdx.x * 256 + threadIdx.x;
    int row = chunk >> 5;
    int c = chunk & 31;
    int v;
    if (flag[0]) {
        v = (int)((const uint*)x)[2 * row];
    } else {
        v = ((const int*)x)[row];
    }
    v = min(max(v, 0), 49999);
    const float4* e = (const float4*)&embed[(size_t)v * 256 + (size_t)c * 8];
    float4 a = e[0], b = e[1];
    uint4 pv;
    pv.x = pack2(a.x, a.y);
    pv.y = pack2(a.z, a.w);
    pv.z = pack2(b.x, b.y);
    pv.w = pack2(b.z, b.w);
    *(uint4*)&out[(size_t)row * 256 + (size_t)c * 8] = pv;
}

// ---------------------------------------------------------------------------
// GEMM (r11-verified): C = A(bf16) * W^T(fp32 inline->bf16) + bias, optional
// GELU; bf16 Cb and/or fp32 Cf outputs. A-tile staged via async
// global_load_lds width=16 (m97 pattern); B-tile reg path (needs fp32->bf16
// VALU convert). __syncthreads drains vmcnt+lgkmcnt -> visibility + anti-
// overwrite covered by the existing two barriers.
// ---------------------------------------------------------------------------
#define GLDS16(gsrc, ldst)                                                    \
    __builtin_amdgcn_global_load_lds(                                         \
        (const __attribute__((address_space(1))) uint*)(gsrc),                \
        (__attribute__((address_space(3))) uint*)(ldst), 16, 0, 0)

__global__ __launch_bounds__(256) void k_gemm_bt(const ushort* __restrict__ A,
                                                 const float* __restrict__ Wf,
                                                 const float* __restrict__ bias,
                                                 ushort* __restrict__ Cb,
                                                 float* __restrict__ Cf,
                                                 int M, int N, int K, int gelu) {
    __shared__ __align__(16) ushort Al[128 * 32];
    __shared__ __align__(16) ushort Bl[128 * 32];
    int tid = threadIdx.x;
    int bm = blockIdx.x, bn = blockIdx.y;
    int wid = tid >> 6, lane = tid & 63;
    int ln = lane & 15, kq = lane >> 4;
    int wm = (wid & 1) * 64, wn = (wid >> 1) * 64;
    int rowA0 = bm * 128, rowB0 = bn * 128;

    f32x4 acc[4][4];
#pragma unroll
    for (int i = 0; i < 4; i++)
#pragma unroll
        for (int j = 0; j < 4; j++) acc[i][j] = (f32x4){0.f, 0.f, 0.f, 0.f};

    int ra = tid >> 2, ca8 = (tid & 3) * 8;  // A-staging coords (16B/lane)

    for (int kt = 0; kt < K; kt += 32) {
        // A tile: async global->LDS, 2 x 16B per thread.
        GLDS16(&A[(size_t)(rowA0 + ra) * K + kt + ca8], &Al[tid * 8]);
        GLDS16(&A[(size_t)(rowA0 + 64 + ra) * K + kt + ca8],
               &Al[2048 + tid * 8]);
        // B tile: reg path with inline fp32->bf16.
#pragma unroll
        for (int c = tid; c < 512; c += 256) {
            int r = c >> 2, c8 = (c & 3) * 8;
            int nb = rowB0 + r;
            uint4 bv = {0u, 0u, 0u, 0u};
            if (nb < N) {
                const float4* wp = (const float4*)&Wf[(size_t)nb * K + kt + c8];
                float4 w0 = wp[0], w1 = wp[1];
                bv.x = pack2(w0.x, w0.y);
                bv.y = pack2(w0.z, w0.w);
                bv.z = pack2(w1.x, w1.y);
                bv.w = pack2(w1.z, w1.w);
            }
            *(uint4*)&Bl[r * 32 + c8] = bv;
        }
        __syncthreads();
        sh8 af[4], bfr[4];
#pragma unroll
        for (int i = 0; i < 4; i++)
            af[i] = *(const sh8*)&Al[(wm + i * 16 + ln) * 32 + kq * 8];
#pragma unroll
        for (int j = 0; j < 4; j++)
            bfr[j] = *(const sh8*)&Bl[(wn + j * 16 + ln) * 32 + kq * 8];
#pragma unroll
        for (int i = 0; i < 4; i++)
#pragma unroll
            for (int j = 0; j < 4; j++)
                acc[i][j] = __builtin_amdgcn_mfma_f32_16x16x32_bf16(
                    af[i], bfr[j], acc[i][j], 0, 0, 0);
        __syncthreads();
    }

#pragma unroll
    for (int i = 0; i < 4; i++)
#pragma unroll
        for (int j = 0; j < 4; j++) {
            int col = rowB0 + wn + j * 16 + ln;
            if (col >= N) continue;
            float bv = bias[col];
#pragma unroll
            for (int reg = 0; reg < 4; reg++) {
                int row = rowA0 + wm + i * 16 + kq * 4 + reg;
                float v = acc[i][j][reg] + bv;
                if (gelu) v = 0.5f * v * (1.0f + erff(v * 0.70710678118f));
                if (Cb) Cb[(size_t)row * N + col] = f2b(v);
                if (Cf) Cf[(size_t)row * N + col] = v;
            }
        }
}

// ---------------------------------------------------------------------------
// GRU recurrence v11 — v8/r11 structure + no-select replication + setprio.
// Change (a): A-tile replication switched from cyclic (row i = batch i&3,
// LDS read (ln&3)*144) to CONSECUTIVE (row i = batch i>>2, LDS read
// (ln>>2)*144). Then lane (kq,ln) reg r = C row 4kq+r = batch (4kq+r)>>2 =
// kq for ALL r: the lane's batch sits in reg 0 of every accumulator -> the
// 9 v_cndmask selects (and b1/b2) are deleted, shortening both VALU issue
// and the MFMA->gates serial chain. Reads remain 4-lane same-address
// broadcasts (lanes 4b..4b+3 read row b) -> conflict-free. Write side
// unchanged (batch kq -> row kq, consistent with the new read mapping).
// Change (b): s_setprio(1) around the MFMA cluster (T5; 2 waves/SIMD give
// the scheduler phase diversity to arbitrate).
// Everything else exactly r11-verified: 32 blocks (4 batches x 1 dir), 512
// threads, 1 output/lane, 12 MFMA/wave, LDS [2][4][144] double-buffer,
// counted-vmcnt asm stream (4 loads + 1 store/step, waits 4,5,6,...,6,2).
// ---------------------------------------------------------------------------
struct PF {
    uint xr, xz, xn, rv;
};

#define GLOAD(dst, off, base, IMM)                                            \
    asm volatile("global_load_ushort %0, %1, %2 offset:" IMM                  \
                 : "=v"(dst)                                                  \
                 : "v"(off), "s"(base))

#define GSTORE(off, data, base)                                               \
    asm volatile("global_store_short %0, %1, %2" ::"v"(off), "v"(data),       \
                 "s"(base))

#define PREF(p)                                                               \
    {                                                                         \
        GLOAD(p.xr, xo_ld, xp, "0");                                          \
        GLOAD(p.xz, xo_ld, xp, "256");                                        \
        GLOAD(p.xn, xo_ld, xp, "512");                                        \
        GLOAD(p.rv, ho_ld, hb, "0");                                          \
        xo_ld += XS;                                                          \
        ho_ld += HS;                                                          \
    }

#define GSTEP(PAR, p, WN, DP)                                                 \
    {                                                                         \
        asm volatile("s_waitcnt vmcnt(" #WN ")");                             \
        __builtin_amdgcn_sched_barrier(0);                                    \
        float xr = __uint_as_float(p.xr << 16);                               \
        float xz = __uint_as_float(p.xz << 16);                               \
        float xn = __uint_as_float(p.xn << 16);                               \
        float rv = __uint_as_float(p.rv << 16);                               \
        if (DP) {                                                             \
            PREF(p)                                                           \
        }                                                                     \
        const ushort* hrd = lds + (PAR)*576 + (ln >> 2) * 144 + kq * 8;       \
        sh8 a0 = *(const sh8*)(hrd);                                          \
        sh8 a1 = *(const sh8*)(hrd + 32);                                     \
        sh8 a2 = *(const sh8*)(hrd + 64);                                     \
        sh8 a3 = *(const sh8*)(hrd + 96);                                     \
        f32x4 accr = (f32x4){0.f, 0.f, 0.f, 0.f};                             \
        f32x4 accz = accr, accn = accr;                                       \
        __builtin_amdgcn_s_setprio(1);                                        \
        accr = __builtin_amdgcn_mfma_f32_16x16x32_bf16(a0, bfrag[0][0], accr, 0, 0, 0); \
        accz = __builtin_amdgcn_mfma_f32_16x16x32_bf16(a0, bfrag[1][0], accz, 0, 0, 0); \
        accn = __builtin_amdgcn_mfma_f32_16x16x32_bf16(a0, bfrag[2][0], accn, 0, 0, 0); \
        accr = __builtin_amdgcn_mfma_f32_16x16x32_bf16(a1, bfrag[0][1], accr, 0, 0, 0); \
        accz = __builtin_amdgcn_mfma_f32_16x16x32_bf16(a1, bfrag[1][1], accz, 0, 0, 0); \
        accn = __builtin_amdgcn_mfma_f32_16x16x32_bf16(a1, bfrag[2][1], accn, 0, 0, 0); \
        accr = __builtin_amdgcn_mfma_f32_16x16x32_bf16(a2, bfrag[0][2], accr, 0, 0, 0); \
        accz = __builtin_amdgcn_mfma_f32_16x16x32_bf16(a2, bfrag[1][2], accz, 0, 0, 0); \
        accn = __builtin_amdgcn_mfma_f32_16x16x32_bf16(a2, bfrag[2][2], accn, 0, 0, 0); \
        accr = __builtin_amdgcn_mfma_f32_16x16x32_bf16(a3, bfrag[0][3], accr, 0, 0, 0); \
        accz = __builtin_amdgcn_mfma_f32_16x16x32_bf16(a3, bfrag[1][3], accz, 0, 0, 0); \
        accn = __builtin_amdgcn_mfma_f32_16x16x32_bf16(a3, bfrag[2][3], accn, 0, 0, 0); \
        __builtin_amdgcn_s_setprio(0);                                        \
        float rg = sigmf(xr + accr[0] + bh_r);                                \
        float zg = sigmf(xz + accz[0] + bh_z);                                \
        float ng = tanhf2(fmaf(rg, accn[0] + bh_n, xn));                      \
        float h = fmaf(zg, hstate - ng, ng);                                  \
        hstate = h;                                                           \
        float sv = h + rv;                                                    \
        uint pk = cvt_pk_bf16(h, sv);                                         \
        lds[(1 - (PAR)) * 576 + ob * 144 + jcol] = (ushort)pk;                \
        uint svb = pk >> 16;                                                  \
        GSTORE(ho_st, svb, hb);                                               \
        ho_st += HS;                                                          \
        asm volatile("s_waitcnt lgkmcnt(0)");                                 \
        __builtin_amdgcn_sched_barrier(0);                                    \
        __builtin_amdgcn_s_barrier();                                         \
        __builtin_amdgcn_sched_barrier(0);                                    \
    }

template <int DS>  // +1 forward, -1 backward
__device__ __forceinline__ void gru_impl(const ushort* __restrict__ xp,
                                         const float* __restrict__ Whh_l,
                                         const float* __restrict__ bhh_l,
                                         ushort* __restrict__ hb,
                                         int dir, int b_base, int t,
                                         ushort* lds) {
    constexpr int XS = DS * 1536;  // xp row stride per time step, bytes
    constexpr int HS = DS * 512;   // hb row stride per time step, bytes
    const int w = t >> 6, l = t & 63;
    const int ln = l & 15, kq = l >> 4;
    const int jcol = (w << 4) + ln;  // output col (and B-frag row)
    const int ob = kq;               // output batch index 0..3

    const float* Wd = Whh_l + (size_t)dir * 384 * 128;
    const float* bhh_d = bhh_l + dir * 384;

    // Whh B-fragments, bf16, resident in VGPRs.
    sh8 bfrag[3][4];
#pragma unroll
    for (int g = 0; g < 3; g++)
#pragma unroll
        for (int kt = 0; kt < 4; kt++) {
            const float4* wp =
                (const float4*)(Wd + (size_t)(g * 128 + jcol) * 128 + kt * 32 + kq * 8);
            float4 w0 = wp[0], w1 = wp[1];
            uint4 pv;
            pv.x = pack2(w0.x, w0.y);
            pv.y = pack2(w0.z, w0.w);
            pv.z = pack2(w1.x, w1.y);
            pv.w = pack2(w1.z, w1.w);
            bfrag[g][kt] = *(sh8*)&pv;
        }

    const float bh_r = bhh_d[jcol];
    const float bh_z = bhh_d[128 + jcol];
    const float bh_n = bhh_d[256 + jcol];
    asm volatile("" ::"v"(bh_r), "v"(bh_z), "v"(bh_n));

    // Running byte voffsets for THIS lane's single output (b_base+ob, jcol).
    const int t0 = (DS > 0) ? 0 : 511;
    int row0 = (b_base + ob) * 512 + t0;
    int xo_ld = row0 * 1536 + (dir * 384 + jcol) * 2;
    int ho_ld = row0 * 512 + (dir * 128 + jcol) * 2;
    int ho_st = ho_ld;

    float hstate = 0.f;

    // zero both h buffers (2 x 4 rows x 144)
    for (int i = t; i < 2 * 576; i += 512) lds[i] = 0;
    __syncthreads();  // full drain; vmcnt==0 from here

    PF pA, pB;
    PREF(pA)  // t0   (4 loads)
    PREF(pB)  // t0+1 (4 loads)

    GSTEP(0, pA, 4, 1)  // s = 0
    GSTEP(1, pB, 5, 1)  // s = 1
    for (int s = 2; s < 510; s += 2) {
        GSTEP(0, pA, 6, 1)
        GSTEP(1, pB, 6, 1)
    }
    GSTEP(0, pA, 6, 0)  // s = 510 (no prefetch)
    GSTEP(1, pB, 2, 0)  // s = 511
}

__global__ __launch_bounds__(512, 1) void k_gru(const ushort* __restrict__ xp,
                                                const float* __restrict__ Whh_l,
                                                const float* __restrict__ bhh_l,
                                                ushort* __restrict__ hb) {
    __shared__ __align__(16) ushort lds[2 * 576];
    const int dir = blockIdx.x & 1;
    const int b_base = (blockIdx.x >> 1) << 2;  // 4 batches per block
    if (dir == 0)
        gru_impl<1>(xp, Whh_l, bhh_l, hb, dir, b_base, threadIdx.x, lds);
    else
        gru_impl<-1>(xp, Whh_l, bhh_l, hb, dir, b_base, threadIdx.x, lds);
}

// ---------------------------------------------------------------------------
// Host launcher. fp32 inputs AND fp32 output; bf16 internally for MFMA.
// Scratch confined to 64 MiB:
//   [0, 48M)  xp (bf16 32768x768) — also hosts embA, then g (16 MiB each)
//   [48,64M)  hb (bf16 32768x256) — W1 out, GRU layers update in place
// ---------------------------------------------------------------------------
extern "C" void kernel_launch(void* const* d_in, const int* in_sizes, int n_in,
                              void* d_out, int out_size, void* d_ws, size_t ws_size,
                              hipStream_t stream) {
    const void* x = d_in[0];
    const float* embed = (const float*)d_in[1];
    const float* W1 = (const float*)d_in[2];
    const float* b1 = (const float*)d_in[3];
    const float* Wih = (const float*)d_in[4];  // [2][2][384][256]
    const float* Whh = (const float*)d_in[5];  // [2][2][384][128]
    const float* bih = (const float*)d_in[6];  // [2][2][384]
    const float* bhh = (const float*)d_in[7];  // [2][2][384]
    const float* W2 = (const float*)d_in[8];
    const float* b2 = (const float*)d_in[9];
    const float* W3 = (const float*)d_in[10];
    const float* b3 = (const float*)d_in[11];

    char* ws = (char*)d_ws;
    ushort* xp = (ushort*)ws;                         // [0, 48M)
    ushort* hb = (ushort*)(ws + 32768ull * 768 * 2);  // [48M, 64M)
    ushort* embA = xp;  // 16 MiB slot, dead after W1 GEMM
    ushort* g = xp;     // reused after last GRU
    int* xflag = (int*)hb;  // transient; dead after k_gather

    // detect x index width, then gather + W1: hb = bf16(embA @ W1^T + b1)
    k_detx<<<1, 256, 0, stream>>>((const uint*)x, xflag);
    k_gather<<<4096, 256, 0, stream>>>(x, embed, xflag, embA);
    k_gemm_bt<<<dim3(256, 2), 256, 0, stream>>>(embA, W1, b1, hb, (float*)0,
                                                32768, 256, 256, 0);

    // layer 0: xp = hb @ Wih[0]^T + bih[0]; GRU updates hb in place
    k_gemm_bt<<<dim3(256, 6), 256, 0, stream>>>(hb, Wih, bih, xp, (float*)0,
                                                32768, 768, 256, 0);
    k_gru<<<32, 512, 0, stream>>>(xp, Whh, bhh, hb);

    // layer 1
    k_gemm_bt<<<dim3(256, 6), 256, 0, stream>>>(hb, Wih + 196608, bih + 768,
                                                xp, (float*)0, 32768, 768, 256, 0);
    k_gru<<<32, 512, 0, stream>>>(xp, Whh + 98304, bhh + 768, hb);

    // head: g = bf16(GELU(hb @ W2^T + b2)); d_out = fp32(g @ W3^T + b3)
    k_gemm_bt<<<dim3(256, 2), 256, 0, stream>>>(hb, W2, b2, g, (float*)0,
                                                32768, 256, 256, 1);
    k_gemm_bt<<<dim3(256, 1), 256, 0, stream>>>(g, W3, b3, (ushort*)0,
                                                (float*)d_out, 32768, 50, 256, 0);
}